// Round 3
// baseline (642.154 us; speedup 1.0000x reference)
//
#include <hip/hip_runtime.h>
#include <hip/hip_bf16.h>
#include <stdint.h>

// Mahalanobis loss: out = mean_n (f_n - mu)^T C (f_n - mu),  N=131072, D=512.
// T0 = F @ Cb via bf16 MFMA (mean folded: w = Cb^T mu), fused epilogue
//   quad[n] = sum_e (T0[n,e] - w[e]) * (fb[n,e] - mu[e])   (bilinear form, exact enough)
// R3: BARRIER-FREE K-loop. R2 proved any __syncthreads in the K-loop forces a
// vmcnt(0) drain (~900 cy HBM round trip per iter). New structure: 8 waves/block,
// all waves read the SAME 64-row F strip (L1-shared A), each wave owns 64 e-cols
// (B from L2-resident Ct). Register prefetch depth-2; wave-private LDS bounce
// holds this wave's own-e bf16 fragments for the epilogue. No __syncthreads
// until after the K-loop.

typedef __attribute__((ext_vector_type(8))) short short8;
typedef __attribute__((ext_vector_type(4))) float floatx4;

static constexpr int NROWS = 131072;
static constexpr int DDIM  = 512;
static constexpr int FS_STRIDE = 136;   // prep_t LDS stride (shorts)
static constexpr int BSTRIDE = 72;      // bounce row stride in shorts (64 + 8 pad)

__device__ __forceinline__ short f2bf(float f) {
  __bf16 b = (__bf16)f;                 // RNE f32->bf16
  return __builtin_bit_cast(short, b);
}
__device__ __forceinline__ float bf2f(short s) {
  __bf16 b = __builtin_bit_cast(__bf16, s);
  return (float)b;
}

// ---- prep A: transpose+convert C -> Ct[e][k] bf16, coalesced via LDS, 16 blocks ----
__global__ __launch_bounds__(256) void maha_prep_t(const float* __restrict__ C,
                                                   short* __restrict__ Ct) {
  __shared__ short T[128 * FS_STRIDE];
  const int bt = blockIdx.x;
  const int k0 = (bt & 3) * 128;
  const int e0 = (bt >> 2) * 128;
  const int rr = threadIdx.x >> 5;       // 0..7  (k row within pass)
  const int cc = threadIdx.x & 31;       // 0..31 (float4 column)
#pragma unroll
  for (int p = 0; p < 16; p++) {
    const int k = p * 8 + rr;
    floatx4 v = *(const floatx4*)(C + (size_t)(k0 + k) * DDIM + e0 + cc * 4);
#pragma unroll
    for (int i = 0; i < 4; i++) T[(cc * 4 + i) * FS_STRIDE + k] = f2bf(v[i]);
  }
  __syncthreads();
  const int er = threadIdx.x >> 4;       // 0..15
  const int kc = threadIdx.x & 15;       // x8 shorts
#pragma unroll
  for (int p = 0; p < 8; p++) {
    const int e = p * 16 + er;
    short8 v = *(const short8*)&T[e * FS_STRIDE + kc * 8];
    *(short8*)(Ct + (size_t)(e0 + e) * DDIM + k0 + kc * 8) = v;
  }
}

// ---- prep B: w[e] = sum_k mu[k]*Ctb[e][k]; zero out. 512 blocks x 64 threads ----
__global__ __launch_bounds__(64) void maha_prep_w(const short* __restrict__ Ct,
                                                  const float* __restrict__ mean,
                                                  float* __restrict__ w,
                                                  float* __restrict__ out) {
  const int e = blockIdx.x;
  const int t = threadIdx.x;
  short8 cv = *(const short8*)(Ct + (size_t)e * DDIM + t * 8);
  float p = 0.f;
#pragma unroll
  for (int i = 0; i < 8; i++) p += mean[t * 8 + i] * bf2f(cv[i]);
#pragma unroll
  for (int off = 32; off > 0; off >>= 1) p += __shfl_down(p, off);
  if (t == 0) {
    w[e] = p;
    if (e == 0) out[0] = 0.0f;   // d_out is poisoned 0xAA before every launch
  }
}

// ---------------- main: barrier-free fused GEMM + quadratic form ----------------
__global__ __launch_bounds__(512, 2) void maha_main(const float* __restrict__ F,
                                                    const float* __restrict__ mean,
                                                    const short* __restrict__ Ct,
                                                    const float* __restrict__ w,
                                                    float* __restrict__ out) {
  __shared__ short bounce[8 * 64 * BSTRIDE];  // per-wave 64x64 bf16 f-tile, 72 KB
  __shared__ float red[8];

  const int t    = threadIdx.x;
  const int lane = t & 63;
  const int wv   = t >> 6;                 // 0..7: wave id = e-range owner
  const int l15  = lane & 15;
  const int quad = lane >> 4;

  const int m0 = blockIdx.x * 64;          // 2048 blocks cover N rows
  const int e0 = wv * 64;

  // A: all 8 waves read identical addresses (L1-shared). k-contiguous 32B per lane.
  const float* Abase = F  + (size_t)(m0 + l15) * DDIM + quad * 8;
  // B: Ct rows e (k-contiguous bf16), wave-private e-range, L2-resident.
  const short* Bbase = Ct + (size_t)(e0 + l15) * DDIM + quad * 8;

  floatx4 pA[2][8];
  short8  pB[2][4];

  auto loadA = [&](int ks, int st) {
#pragma unroll
    for (int mi = 0; mi < 4; mi++) {
      const floatx4* p = (const floatx4*)(Abase + mi * 16 * DDIM + ks * 32);
      pA[st][mi * 2]     = p[0];
      pA[st][mi * 2 + 1] = p[1];
    }
  };
  auto loadB = [&](int ks, int st) {
#pragma unroll
    for (int fj = 0; fj < 4; fj++)
      pB[st][fj] = *(const short8*)(Bbase + fj * 16 * DDIM + ks * 32);
  };

  floatx4 acc[4][4];
#pragma unroll
  for (int i = 0; i < 4; i++)
#pragma unroll
    for (int j = 0; j < 4; j++) acc[i][j] = floatx4{0.f, 0.f, 0.f, 0.f};

  loadA(0, 0); loadB(0, 0);
  loadA(1, 1); loadB(1, 1);

  short* myb = bounce + wv * 64 * BSTRIDE;

#pragma unroll
  for (int c = 0; c < 16; ++c) {
    const int st = c & 1;
    // fp32 -> bf16 fragments (consumes pA[st])
    short8 af[4];
#pragma unroll
    for (int mi = 0; mi < 4; mi++)
#pragma unroll
      for (int j = 0; j < 4; j++) {
        af[mi][j]     = f2bf(pA[st][mi * 2][j]);
        af[mi][j + 4] = f2bf(pA[st][mi * 2 + 1][j]);
      }
    if (c + 2 < 16) loadA(c + 2, st);      // A refill early: ~1.5 iters of lead (HBM)
    // park own-e-range fragments for the epilogue (wave-private, no barrier)
    if ((c >> 1) == wv) {
      const int half = c & 1;
#pragma unroll
      for (int mi = 0; mi < 4; mi++)
        *(short8*)&myb[(mi * 16 + l15) * BSTRIDE + half * 32 + quad * 8] = af[mi];
    }
#pragma unroll
    for (int fj = 0; fj < 4; fj++)
#pragma unroll
      for (int mi = 0; mi < 4; mi++)
        acc[mi][fj] = __builtin_amdgcn_mfma_f32_16x16x32_bf16(af[mi], pB[st][fj],
                                                              acc[mi][fj], 0, 0, 0);
    if (c + 2 < 16) loadB(c + 2, st);      // B refill after its consumers (L2, ~1 iter lead)
  }

  // Epilogue: psum = sum_e (acc - w[e]) * (fb - mu[e]); fb from wave-private bounce.
  float psum = 0.f;
#pragma unroll
  for (int fj = 0; fj < 4; fj++) {
    const int e_loc = fj * 16 + l15;
    const float wj = w[e0 + e_loc];
    const float mj = mean[e0 + e_loc];
#pragma unroll
    for (int mi = 0; mi < 4; mi++) {
      const int rbase = mi * 16 + quad * 4;
#pragma unroll
      for (int r = 0; r < 4; r++) {
        const float fv = bf2f(myb[(rbase + r) * BSTRIDE + e_loc]);
        psum += (acc[mi][fj][r] - wj) * (fv - mj);
      }
    }
  }

  // wave reduce -> block reduce -> one atomic per block
#pragma unroll
  for (int off = 32; off > 0; off >>= 1) psum += __shfl_down(psum, off);
  if (lane == 0) red[wv] = psum;
  __syncthreads();
  if (t == 0) {
    float tot = 0.f;
#pragma unroll
    for (int i = 0; i < 8; i++) tot += red[i];
    atomicAdd(out, tot * (1.0f / (float)NROWS));
  }
}

extern "C" void kernel_launch(void* const* d_in, const int* in_sizes, int n_in,
                              void* d_out, int out_size, void* d_ws, size_t ws_size,
                              hipStream_t stream) {
  const float* feature = (const float*)d_in[0];   // [131072, 512] fp32
  const float* mean    = (const float*)d_in[1];   // [512] fp32
  const float* invcov  = (const float*)d_in[2];   // [512, 512] fp32
  float* out = (float*)d_out;                     // scalar fp32

  // workspace: w[512] fp32 at +0, Ct[512*512] bf16 at +4096  (~516 KB)
  float* w  = (float*)d_ws;
  short* Ct = (short*)((char*)d_ws + 4096);

  maha_prep_t<<<16, 256, 0, stream>>>(invcov, Ct);
  maha_prep_w<<<512, 64, 0, stream>>>(Ct, mean, w, out);
  maha_main<<<2048, 512, 0, stream>>>(feature, mean, Ct, w, out);
}

// Round 4
// 427.374 us; speedup vs baseline: 1.5026x; 1.5026x over previous
//
#include <hip/hip_runtime.h>
#include <hip/hip_bf16.h>
#include <stdint.h>

// Mahalanobis loss via Gram reformulation:
//   mean_n (f_n-mu)^T C (f_n-mu)
//     = (1/N)[ <C, G> - sum_{d,e} C_de (coef_d mu_e + mu_d coef_e) ],
//   G = Fb^T Fb (bf16 inputs, fp32 accum), s = sum_n fb_n, coef = s - (N/2) mu.
// Why: reads F exactly ONCE (268 MB), C stays fp32 (better accuracy), and with
// G symmetric only 10 of 16 128x128 tiles are computed -> 20480 barrier-iters
// vs R2's 65536 (the ~1600cy/barrier-iter cost was R2's measured limiter).
// K = n (rows) forces an LDS transpose: register 4x4 transpose + XOR bank
// swizzle (address-only, verified 32-bank-spread for the b64 writes).
// R3 lesson: __launch_bounds__ 2nd arg acts as min-BLOCKS -> VGPR cap; (256,2)
// caps at 256 VGPR under either interpretation (no spills).

typedef __attribute__((ext_vector_type(8))) short short8;
typedef __attribute__((ext_vector_type(4))) short short4v;
typedef __attribute__((ext_vector_type(4))) float floatx4;

static constexpr int NROWS = 131072;
static constexpr int DDIM  = 512;
static constexpr int AST   = 72;          // LDS row stride in shorts (64 n + 8 pad)
static constexpr int SLOT  = 128 * AST;   // shorts per double-buffer slot

__device__ __forceinline__ short f2bf(float f) {
  __bf16 b = (__bf16)f;                   // RNE f32->bf16
  return __builtin_bit_cast(short, b);
}
__device__ __forceinline__ float bf2f(short s) {
  __bf16 b = __builtin_bit_cast(__bf16, s);
  return (float)b;
}

// ---- zero-init: s[512] and out (both poisoned 0xAA before every launch) ----
__global__ __launch_bounds__(512) void maha_zero(float* __restrict__ s_ws,
                                                 float* __restrict__ out) {
  s_ws[threadIdx.x] = 0.0f;
  if (threadIdx.x == 0) out[0] = 0.0f;
}

// ---- main: symmetric Gram tiles, fused <C,G> epilogue + s accumulation ----
__global__ __launch_bounds__(256, 2) void maha_gram(const float* __restrict__ F,
                                                    const float* __restrict__ C,
                                                    float* __restrict__ s_ws,
                                                    float* __restrict__ out) {
  __shared__ short As[2 * SLOT];          // A = F columns [128*ti, +128), [d][n] bf16
  __shared__ short Bs[2 * SLOT];          // B = F columns [128*tj, +128)
  __shared__ float sred[512];
  __shared__ float red[4];

  static const int TI[10] = {0,0,0,0,1,1,1,2,2,3};
  static const int TJ[10] = {0,1,2,3,1,2,3,2,3,3};

  // swizzle: groups of 80 = 8 slabs x 10 tiles; co-slab blocks share bid%8
  // (same XCD) and sit within one 80-bid window (temporal locality in L2).
  const int bid  = blockIdx.x;
  const int gg   = bid / 80;
  const int rr   = bid % 80;
  const int slab = gg * 8 + (rr & 7);     // 0..127, 1024 rows each
  const int tile = rr >> 3;               // 0..9
  const int ti = TI[tile], tj = TJ[tile];
  const bool diag = (ti == tj);

  const int th = threadIdx.x;
  // ---- staging mapping: 128 threads per matrix (As / Bs) ----
  const int half = th >> 7;               // 0 -> As, 1 -> Bs
  const int t2   = th & 127;
  const int tp   = t2 & 31;               // d-quad owner (d = 4*tp + dd)
  const int tn   = t2 >> 5;               // 0..3
  const int colbase = 128 * (half ? tj : ti);
  short* mybuf = half ? Bs : As;

  // rotations for conflict-free b64 LDS writes (32 distinct banks/instr):
  const int noff = (tn + (tp >> 2)) & 3;  // n-sub rotation (bits 2-3 of tp)
  const int tphi = tp >> 4;               // k rotation (bit 4 of tp)
  const int gsw  = 8 * (tp & 7);          // XOR address swizzle = 8*((d>>2)&7)

  const float* gbase = F + (size_t)slab * 1024 * DDIM + colbase + 4 * tp;

  floatx4 v[4][4];                        // single fp32 prefetch stage (64 VGPR)

  auto loadG = [&](int c) {
#pragma unroll
    for (int k = 0; k < 4; k++) {
      const int kq = k ^ tphi;
      const int nb = 4 * kq + noff;       // n-block 0..15 within the 64-row chunk
      const float* p = gbase + (size_t)(c * 64 + 4 * nb) * DDIM;
#pragma unroll
      for (int nn = 0; nn < 4; nn++)
        v[k][nn] = *(const floatx4*)(p + nn * DDIM);
    }
  };

  float s_part[4] = {0.f, 0.f, 0.f, 0.f};
  const bool sacc = diag && (half == 0);  // diag blocks accumulate s once per col

  auto cvtwrite = [&](int slot) {
#pragma unroll
    for (int k = 0; k < 4; k++) {
      const int kq = k ^ tphi;
      const int nb = 4 * kq + noff;
      const int naddr = (4 * nb) ^ gsw;   // XOR bits>=3 only: 4-runs move as units
#pragma unroll
      for (int dd = 0; dd < 4; dd++) {
        short4v pk;                        // register 4x4 transpose: column dd
        pk[0] = f2bf(v[k][0][dd]); pk[1] = f2bf(v[k][1][dd]);
        pk[2] = f2bf(v[k][2][dd]); pk[3] = f2bf(v[k][3][dd]);
        *(short4v*)&mybuf[slot * SLOT + (4 * tp + dd) * AST + naddr] = pk;
        if (sacc)
          s_part[dd] += bf2f(pk[0]) + bf2f(pk[1]) + bf2f(pk[2]) + bf2f(pk[3]);
      }
    }
  };

  // ---- MFMA mapping: 2x2 wave grid over the 128x128 G-tile ----
  const int wave = th >> 6, lane = th & 63;
  const int wm = wave >> 1, wn = wave & 1;
  const int l15 = lane & 15, quad = lane >> 4;

  int aoff[4], swA[4], boff[4], swB[4];
#pragma unroll
  for (int mi = 0; mi < 4; mi++) {
    const int d = wm * 64 + mi * 16 + l15;
    aoff[mi] = d * AST;  swA[mi] = 8 * ((d >> 2) & 7);
    const int e = wn * 64 + mi * 16 + l15;
    boff[mi] = e * AST;  swB[mi] = 8 * ((e >> 2) & 7);
  }

  floatx4 acc[4][4];
#pragma unroll
  for (int i = 0; i < 4; i++)
#pragma unroll
    for (int j = 0; j < 4; j++) acc[i][j] = floatx4{0.f, 0.f, 0.f, 0.f};

  loadG(0);
  cvtwrite(0);
  loadG(1);

#pragma unroll 2
  for (int c = 0; c < 16; ++c) {
    const int slot = c & 1;
    __syncthreads();                      // slot ready; other slot free
    short8 af[2][4], bfr[2][4];
#pragma unroll
    for (int ks = 0; ks < 2; ks++) {
#pragma unroll
      for (int mi = 0; mi < 4; mi++)
        af[ks][mi] = *(const short8*)&As[slot * SLOT + aoff[mi] +
                                         ((ks * 32 + quad * 8) ^ swA[mi])];
#pragma unroll
      for (int fj = 0; fj < 4; fj++)
        bfr[ks][fj] = *(const short8*)&Bs[slot * SLOT + boff[fj] +
                                          ((ks * 32 + quad * 8) ^ swB[fj])];
    }
    if (c < 15) cvtwrite(slot ^ 1);       // chunk c+1 (regs loaded at iter c-1)
    if (c < 14) loadG(c + 2);             // issued BEFORE MFMA: ~1 iter of flight
#pragma unroll
    for (int ks = 0; ks < 2; ks++)
#pragma unroll
      for (int mi = 0; mi < 4; mi++)
#pragma unroll
        for (int fj = 0; fj < 4; fj++)
          acc[mi][fj] = __builtin_amdgcn_mfma_f32_16x16x32_bf16(
              af[ks][mi], bfr[ks][fj], acc[mi][fj], 0, 0, 0);
  }

  // ---- epilogue: psum = sum W_de * G_de, W = C_ij (+ C_ji^T if offdiag) ----
  const int d0 = ti * 128, e0 = tj * 128;
  float psum = 0.f;
#pragma unroll
  for (int mi = 0; mi < 4; mi++) {
#pragma unroll
    for (int fj = 0; fj < 4; fj++) {
      const int dg = d0 + wm * 64 + mi * 16 + quad * 4;
      const int eg = e0 + wn * 64 + fj * 16 + l15;
#pragma unroll
      for (int r2 = 0; r2 < 4; r2++) {
        float wgt = C[(size_t)(dg + r2) * DDIM + eg];
        if (!diag) wgt += C[(size_t)eg * DDIM + dg + r2];
        psum += wgt * acc[mi][fj][r2];
      }
    }
  }

#pragma unroll
  for (int off = 32; off > 0; off >>= 1) psum += __shfl_down(psum, off);
  if (lane == 0) red[wave] = psum;
  if (sacc) {                             // park s partials (th < 128 only)
#pragma unroll
    for (int dd = 0; dd < 4; dd++) sred[(4 * tp + dd) * 4 + tn] = s_part[dd];
  }
  __syncthreads();
  if (th == 0) {
    const float tot = red[0] + red[1] + red[2] + red[3];
    atomicAdd(out, tot * (1.0f / (float)NROWS));
  }
  if (diag && th < 128) {
    const float sd = sred[th * 4] + sred[th * 4 + 1] + sred[th * 4 + 2] + sred[th * 4 + 3];
    atomicAdd(&s_ws[ti * 128 + th], sd);
  }
}

// ---- correction: out += -(1/N) sum_{d,e} C_de (coef_d mu_e + mu_d coef_e) ----
__global__ __launch_bounds__(256) void maha_corr(const float* __restrict__ C,
                                                 const float* __restrict__ mu,
                                                 const float* __restrict__ s_ws,
                                                 float* __restrict__ out) {
  __shared__ float red[4];
  const int b = blockIdx.x;               // 128 blocks x 4 d-rows
  const int th = threadIdx.x;
  float cd[4], md[4];
#pragma unroll
  for (int dd = 0; dd < 4; dd++) {
    const int d = b * 4 + dd;
    md[dd] = mu[d];
    cd[dd] = s_ws[d] - 0.5f * (float)NROWS * md[dd];
  }
  float p = 0.f;
#pragma unroll
  for (int rep = 0; rep < 2; rep++) {
    const int e = th + rep * 256;
    const float me = mu[e];
    const float ce = s_ws[e] - 0.5f * (float)NROWS * me;
#pragma unroll
    for (int dd = 0; dd < 4; dd++)
      p += C[(size_t)(b * 4 + dd) * DDIM + e] * (cd[dd] * me + md[dd] * ce);
  }
  const int lane = th & 63, wave = th >> 6;
#pragma unroll
  for (int off = 32; off > 0; off >>= 1) p += __shfl_down(p, off);
  if (lane == 0) red[wave] = p;
  __syncthreads();
  if (th == 0)
    atomicAdd(out, -(red[0] + red[1] + red[2] + red[3]) * (1.0f / (float)NROWS));
}

extern "C" void kernel_launch(void* const* d_in, const int* in_sizes, int n_in,
                              void* d_out, int out_size, void* d_ws, size_t ws_size,
                              hipStream_t stream) {
  const float* feature = (const float*)d_in[0];   // [131072, 512] fp32
  const float* mean    = (const float*)d_in[1];   // [512] fp32
  const float* invcov  = (const float*)d_in[2];   // [512, 512] fp32
  float* out = (float*)d_out;                     // scalar fp32
  float* s_ws = (float*)d_ws;                     // s[512] fp32 (2 KB)

  maha_zero<<<1, 512, 0, stream>>>(s_ws, out);
  maha_gram<<<1280, 256, 0, stream>>>(feature, invcov, s_ws, out);
  maha_corr<<<128, 256, 0, stream>>>(invcov, mean, s_ws, out);
}